// Round 16
// baseline (352.103 us; speedup 1.0000x reference)
//
#include <hip/hip_runtime.h>
#include <cstdint>
#include <cstddef>

typedef unsigned short u16;
typedef __attribute__((ext_vector_type(8))) __bf16 bf16x8;
typedef __attribute__((ext_vector_type(4))) float f32x4;
typedef __attribute__((ext_vector_type(16))) float f32x16;
typedef __attribute__((ext_vector_type(2))) uint32_t u32x2;
typedef __attribute__((ext_vector_type(4))) float float4v;

#define BATCH 4
#define S_LEN 2048
#define DMODEL 1024
#define NHEAD 16
#define HDIM 64
#define MROWS (BATCH * S_LEN)   // 8192
#define LOG2E 1.4426950408889634f
#define SC_L (0.125f * LOG2E)   // 1/sqrt(64) * log2(e)

__device__ __forceinline__ u16 f2bf(float f) {
  uint32_t u = __float_as_uint(f);
  u += 0x7fffu + ((u >> 16) & 1u);   // RNE
  return (u16)(u >> 16);
}

#if __has_builtin(__builtin_amdgcn_cvt_pk_bf16_f32)
__device__ __forceinline__ uint32_t packbf2(float a, float b) {
  auto t = __builtin_amdgcn_cvt_pk_bf16_f32(a, b);
  uint32_t u;
  __builtin_memcpy(&u, &t, 4);
  return u;
}
#else
__device__ __forceinline__ uint32_t packbf2(float a, float b) {
  uint32_t ua = __float_as_uint(a) + 0x8000u;
  uint32_t ub = __float_as_uint(b) + 0x8000u;
  return (ub & 0xFFFF0000u) | (ua >> 16);
}
#endif

#if __has_builtin(__builtin_amdgcn_exp2f)
#define EXP2(x) __builtin_amdgcn_exp2f(x)
#else
#define EXP2(x) exp2f(x)
#endif

typedef __attribute__((address_space(1))) void gvoid_t;
typedef __attribute__((address_space(3))) void svoid_t;
__device__ __forceinline__ void gl_lds16(const void* g, void* s) {
  __builtin_amdgcn_global_load_lds((gvoid_t*)g, (svoid_t*)s, 16, 0, 0);
}

// ---------------- fused prep: x cvt (8192 blks) + W transpose/cvt (4096 blks)
//                  + mask*LOG2E (32 blks) ----------------
#define NB_CVT (MROWS * DMODEL / 4 / 256)   // 8192
#define NB_W   4096
__global__ __launch_bounds__(256) void prep_kernel(const float4v* __restrict__ x,
                                                   u32x2* __restrict__ xb,
                                                   const float* __restrict__ W0,
                                                   const float* __restrict__ W1,
                                                   const float* __restrict__ W2,
                                                   const float* __restrict__ W3,
                                                   u16* __restrict__ Wall,
                                                   const float* __restrict__ mask,
                                                   float* __restrict__ mL) {
  __shared__ float tile[32][33];
  const int bid = blockIdx.x;
  const int tid = threadIdx.x;
  if (bid < NB_CVT) {
    const int i = bid * 256 + tid;
    float4v v = x[i];
    u32x2 o;
    o.x = packbf2(v.x, v.y);
    o.y = packbf2(v.z, v.w);
    xb[i] = o;
    return;
  }
  if (bid >= NB_CVT + NB_W) {   // mask * log2e
    const int i = (bid - NB_CVT - NB_W) * 256 + tid;
    mL[i] = mask[i] * LOG2E;
    return;
  }
  const int r = bid - NB_CVT;        // 0..4095
  const int z = r >> 10;             // weight index
  const int rem = r & 1023;
  const float* W = (z == 0) ? W0 : (z == 1) ? W1 : (z == 2) ? W2 : W3;
  u16* Wt = Wall + (size_t)z * DMODEL * DMODEL;
  const int n0 = (rem & 31) * 32, k0 = (rem >> 5) * 32;
  const int xx = tid & 31, y = tid >> 5;   // flattened (32,8)
  for (int yy = y; yy < 32; yy += 8)
    tile[yy][xx] = W[(size_t)(k0 + yy) * DMODEL + n0 + xx];
  __syncthreads();
  for (int yy = y; yy < 32; yy += 8)
    Wt[(size_t)(n0 + yy) * DMODEL + k0 + xx] = f2bf(tile[xx][yy]);
}

// ---------------- 256^2 8-phase-style QKV GEMM (R16) ----------------
// Guide §5 template, m198 variant (linear LDS) + T5 setprio (m224: +34-39%
// on 8-phase-noswz). Regime arithmetic: per phase a wave does 16 MFMA +
// 12 ds_read_b128 (~250-400 cyc/SIMD @2 waves); staged loads get 2-4 phases
// (500-1400 cyc) of cover >= L2/HBM latency. At 128^2/BK32 per-barrier
// compute was ~300cyc < latency -> structurally unhideable (R5/R6/R8).
// Poisons avoided: __launch_bounds__(512) with NO 2nd arg (R2/R13/R14
// 3-strike rule; ~210 VGPR < 256 at LDS-forced 2 waves/SIMD); buffer
// indices all LITERAL (R6); vmcnt(0) only at tile boundaries, fenced by
// sched_barrier(0); raw s_barrier per phase (no __syncthreads drain - R5
// poison); ds_read->MFMA waits left to compiler dataflow.
// Race audit: (a) buf[nxt] written only after its last reads (tile t-1)
// completed pre-boundary-barrier (lgkm waits are dataflow-forced before
// that tile's MFMAs); (b) buf[cur] reads only after each thread drained
// its OWN 8 staging loads (vmcnt(0)) then crossed the boundary s_barrier
// -> all threads' loads landed; (c) next-tile ds_reads cannot hoist above
// the boundary (sched_barrier(0) pair); (d) intra-tile hoisting across
// phase barriers touches only stable buffers - harmless. Barriers are
// unconditional & uniform (no divergence deadlock).
// Waves: 8 (2 row-halves x 4 col-quarters); per-wave output 128x64 =
// acc[8][4]; 4 phases/K-tile, each = one C-quadrant (4i x 2j x 2kk = 16
// MFMA, 12 ds_read_b128). Staging: 8 gl_lds/thread/K-tile in pairs
// {A-rows h*64.., B-rows h*64..}; pairs 0,1 issue at phase 1, pair 2 at
// phase 2, pair 3 at phase 3 -> newest has ~2 phases cover at boundary.
__global__ __launch_bounds__(512) void gemm256_qkv(const u16* __restrict__ A,
                                                   const u16* __restrict__ Bt,
                                                   const float* __restrict__ b0,
                                                   const float* __restrict__ b1,
                                                   const float* __restrict__ b2,
                                                   u16* __restrict__ oQ,
                                                   u16* __restrict__ oK,
                                                   u16* __restrict__ oV) {
  __shared__ u16 As[2][256 * 64];   // 128KB total (R14 proved static OK)
  __shared__ u16 Bs[2][256 * 64];
  const int tid = threadIdx.x;
  const int wid = tid >> 6;         // 0..7
  const int lane = tid & 63;
  const int l16 = lane & 15;
  const int g4 = lane >> 4;
  const int wr = wid >> 2;          // 0..1  row half
  const int wc = wid & 3;           // 0..3  col quarter
  const int m0 = blockIdx.x * 256;
  const int n0 = blockIdx.y * 256;

  const int srow = tid >> 3;        // 0..63
  const int sk = (tid & 7) * 8;
  const u16* gA = A + (size_t)(m0 + srow) * DMODEL + sk;
  const u16* gB = Bt + (size_t)(n0 + srow) * DMODEL + sk;

  f32x4 acc[8][4];
#pragma unroll
  for (int i = 0; i < 8; ++i)
#pragma unroll
    for (int j = 0; j < 4; ++j) acc[i][j] = (f32x4){0.f, 0.f, 0.f, 0.f};

  // stage pair h (A rows h*64.. and B rows h*64.., k-slice of tile t)
#define STGP(buf, h, t)                                                     \
  gl_lds16(gA + (size_t)(h) * 64 * DMODEL + (size_t)(t) * 64,               \
           (char*)&As[buf][0] + (h) * 8192 + wid * 1024);                   \
  gl_lds16(gB + (size_t)(h) * 64 * DMODEL + (size_t)(t) * 64,               \
           (char*)&Bs[buf][0] + (h) * 8192 + wid * 1024);

  // one C-quadrant: rows qi..qi+3 (of 8), cols qj..qj+1 (of 4), full K=64
#define PHASE(buf, qi, qj)                                                  \
  {                                                                         \
    const u16* Ab = &As[buf][0];                                            \
    const u16* Bb = &Bs[buf][0];                                            \
    bf16x8 af[4][2], bfv[2][2];                                             \
    _Pragma("unroll") for (int i = 0; i < 4; ++i)                           \
      _Pragma("unroll") for (int kk = 0; kk < 2; ++kk)                      \
        af[i][kk] = *(const bf16x8*)(Ab + (wr * 128 + ((qi) + i) * 16 + l16) * 64 + kk * 32 + g4 * 8); \
    _Pragma("unroll") for (int j = 0; j < 2; ++j)                           \
      _Pragma("unroll") for (int kk = 0; kk < 2; ++kk)                      \
        bfv[j][kk] = *(const bf16x8*)(Bb + (wc * 64 + ((qj) + j) * 16 + l16) * 64 + kk * 32 + g4 * 8); \
    __builtin_amdgcn_s_setprio(1);                                          \
    _Pragma("unroll") for (int i = 0; i < 4; ++i)                           \
      _Pragma("unroll") for (int j = 0; j < 2; ++j)                         \
        _Pragma("unroll") for (int kk = 0; kk < 2; ++kk)                    \
          acc[(qi) + i][(qj) + j] = __builtin_amdgcn_mfma_f32_16x16x32_bf16(\
              af[i][kk], bfv[j][kk], acc[(qi) + i][(qj) + j], 0, 0, 0);     \
    __builtin_amdgcn_s_setprio(0);                                          \
  }

#define TILE(cur, nxt, t, HAS_NEXT)                                         \
  {                                                                         \
    PHASE(cur, 0, 0)                                                        \
    if (HAS_NEXT) { STGP(nxt, 0, (t) + 1) STGP(nxt, 1, (t) + 1) }           \
    __builtin_amdgcn_s_barrier();                                           \
    PHASE(cur, 4, 0)                                                        \
    if (HAS_NEXT) { STGP(nxt, 2, (t) + 1) }                                 \
    __builtin_amdgcn_s_barrier();                                           \
    PHASE(cur, 0, 2)                                                        \
    if (HAS_NEXT) { STGP(nxt, 3, (t) + 1) }                                 \
    __builtin_amdgcn_s_barrier();                                           \
    PHASE(cur, 4, 2)                                                        \
    asm volatile("s_waitcnt vmcnt(0)" ::: "memory");                        \
    __builtin_amdgcn_sched_barrier(0);                                      \
    __builtin_amdgcn_s_barrier();                                           \
    __builtin_amdgcn_sched_barrier(0);                                      \
  }

  // prologue: stage tile 0 fully, drain, publish
  STGP(0, 0, 0) STGP(0, 1, 0) STGP(0, 2, 0) STGP(0, 3, 0)
  asm volatile("s_waitcnt vmcnt(0)" ::: "memory");
  __builtin_amdgcn_sched_barrier(0);
  __builtin_amdgcn_s_barrier();
  __builtin_amdgcn_sched_barrier(0);

  for (int t2 = 0; t2 < 16; t2 += 2) {
    TILE(0, 1, t2, true)
    TILE(1, 0, t2 + 1, (t2 + 2 < 16))
  }
#undef STGP
#undef PHASE
#undef TILE

  const int seg = n0 >> 10;   // uniform per block (1024 % 256 == 0)
  const float* bp = (seg == 0) ? b0 : (seg == 1 ? b1 : b2);
#pragma unroll
  for (int i = 0; i < 8; ++i) {
#pragma unroll
    for (int j = 0; j < 4; ++j) {
      const int coll = n0 + wc * 64 + j * 16 + l16;
      const int cseg = coll & 1023;
      const float bval = bp[cseg];
#pragma unroll
      for (int r = 0; r < 4; ++r) {
        const int rowg = m0 + wr * 128 + i * 16 + g4 * 4 + r;
        const float v = acc[i][j][r] + bval;
        const int b = rowg >> 11, s = rowg & (S_LEN - 1);
        const int h = cseg >> 6, d = cseg & (HDIM - 1);
        if (seg == 2) {   // V transposed: [B,NH,HD,S]
          oV[(((size_t)(b * NHEAD + h) * HDIM + d) << 11) + s] = f2bf(v);
        } else {
          u16* op = (seg == 0) ? oQ : oK;
          op[((size_t)((b * NHEAD + h) * S_LEN + s) << 6) + d] = f2bf(v);
        }
      }
    }
  }
}

// ---------------- m97-style GEMM, 2 K-subtiles per barrier round (R3) ----------------
// O-projection only (N=1024: 512 blocks = 2/CU). fp32 out row-major.
// 128^2 pipelining ledger CLOSED (R5/R6/R8: serial wins at this tile size).
template <int MODE>
__global__ __launch_bounds__(256) void gemm128(const u16* __restrict__ A,
                                               const u16* __restrict__ Bt,
                                               const float* __restrict__ b0,
                                               const float* __restrict__ b1,
                                               const float* __restrict__ b2,
                                               void* __restrict__ o0,
                                               void* __restrict__ o1,
                                               void* __restrict__ o2) {
  __shared__ u16 As[2 * 128 * 32];   // [subtile][row][k32]
  __shared__ u16 Bs[2 * 128 * 32];
  const int tid = threadIdx.x;
  const int wid = tid >> 6;
  const int lane = tid & 63;
  const int l16 = lane & 15;
  const int g4 = lane >> 4;
  const int m0 = blockIdx.x * 128;
  const int n0 = blockIdx.y * 128;
  const int wm = (wid & 1) * 64;
  const int wn = (wid >> 1) * 64;

  const int srow = tid >> 2;
  const int sk = (tid & 3) * 8;
  const u16* gA = A + (size_t)(m0 + srow) * DMODEL + sk;
  const u16* gB = Bt + (size_t)(n0 + srow) * DMODEL + sk;
  char* sA = (char*)As + wid * 1024;
  char* sB = (char*)Bs + wid * 1024;

  f32x4 acc[4][4];
#pragma unroll
  for (int i = 0; i < 4; ++i)
#pragma unroll
    for (int j = 0; j < 4; ++j) acc[i][j] = (f32x4){0.f, 0.f, 0.f, 0.f};

  for (int k0 = 0; k0 < DMODEL; k0 += 64) {
    __syncthreads();
    gl_lds16(gA + k0, sA);
    gl_lds16(gA + (size_t)64 * DMODEL + k0, sA + 4096);
    gl_lds16(gB + k0, sB);
    gl_lds16(gB + (size_t)64 * DMODEL + k0, sB + 4096);
    gl_lds16(gA + k0 + 32, sA + 8192);
    gl_lds16(gA + (size_t)64 * DMODEL + k0 + 32, sA + 12288);
    gl_lds16(gB + k0 + 32, sB + 8192);
    gl_lds16(gB + (size_t)64 * DMODEL + k0 + 32, sB + 12288);
    __syncthreads();

#pragma unroll
    for (int kk = 0; kk < 2; ++kk) {
      const u16* Ab = As + kk * 4096;
      const u16* Bb = Bs + kk * 4096;
      bf16x8 af[4], bfr[4];
#pragma unroll
      for (int i = 0; i < 4; ++i)
        af[i] = *(const bf16x8*)(Ab + (wm + i * 16 + l16) * 32 + g4 * 8);
#pragma unroll
      for (int j = 0; j < 4; ++j)
        bfr[j] = *(const bf16x8*)(Bb + (wn + j * 16 + l16) * 32 + g4 * 8);
#pragma unroll
      for (int i = 0; i < 4; ++i)
#pragma unroll
        for (int j = 0; j < 4; ++j)
          acc[i][j] = __builtin_amdgcn_mfma_f32_16x16x32_bf16(af[i], bfr[j],
                                                              acc[i][j], 0, 0, 0);
    }
  }

  const int seg = n0 >> 10;   // wave-uniform
  const float* bp = (MODE == 1 || seg == 0) ? b0 : (seg == 1 ? b1 : b2);
  void* op = (MODE == 1 || seg == 0) ? o0 : (seg == 1 ? o1 : o2);

#pragma unroll
  for (int i = 0; i < 4; ++i) {
#pragma unroll
    for (int j = 0; j < 4; ++j) {
      const int coll = n0 + wn + j * 16 + l16;
      const int cseg = coll & 1023;
      const float bval = bp[cseg];
#pragma unroll
      for (int r = 0; r < 4; ++r) {
        const int rowg = m0 + wm + i * 16 + g4 * 4 + r;
        const float v = acc[i][j][r] + bval;
        if (MODE == 0) {
          const int b = rowg >> 11, s = rowg & (S_LEN - 1);
          const int h = cseg >> 6, d = cseg & (HDIM - 1);
          if (seg == 2) {
            ((u16*)op)[(((size_t)(b * NHEAD + h) * HDIM + d) << 11) + s] = f2bf(v);
          } else {
            ((u16*)op)[((size_t)((b * NHEAD + h) * S_LEN + s) << 6) + d] = f2bf(v);
          }
        } else {
          ((float*)op)[(size_t)rowg * DMODEL + cseg] = v;
        }
      }
    }
  }
}

// ---------------- flash attention v4 (measured best: 94.2us, FINAL) ----------------
// CLOSED ledger (8 falsified variants): R1 dbuf/T14/T5 neutral; R2 reg-cap
// spill 3x; R4 32q/wave +13us; R7 in-loop LOG2E +5.6us; R9 lacc->VALU +6us;
// R10 KVBLK=128 +1.6us; R11 LDS-free 2.2x; R13 key-split occupancy +13us.
__global__ __launch_bounds__(256, 2) void attn4_kernel(const u16* __restrict__ Q,
                                                       const u16* __restrict__ K,
                                                       const u16* __restrict__ Vt,
                                                       const float* __restrict__ maskL,
                                                       u16* __restrict__ ctx) {
  __shared__ u16 Ks[64 * 72];   // [key][d]
  __shared__ u16 Vs[64 * 72];   // [d][key'] (pi-permuted keys)

  const int tid = threadIdx.x;
  const int wid = tid >> 6;
  const int lane = tid & 63;
  const int l32 = lane & 31;
  const int hi = lane >> 5;
  const int flat = blockIdx.y * gridDim.x + blockIdx.x;
  const int nf = (flat & 7) * 64 + (flat >> 3);
  const int bx = nf & 7;
  const int bh = nf >> 3;
  const int b = bh >> 4;
  const int h = bh & 15;
  const int qw0 = bx * 256 + wid * 64;

  const u16* Qbase = Q + (size_t)bh * S_LEN * HDIM;
  bf16x8 aq[2][4];
#pragma unroll
  for (int qh = 0; qh < 2; ++qh)
#pragma unroll
    for (int c = 0; c < 4; ++c)
      aq[qh][c] = *(const bf16x8*)(Qbase + (size_t)(qw0 + qh * 32 + l32) * HDIM +
                                   c * 16 + hi * 8);

  union { u16 s[8]; bf16x8 v; } onesu;
#pragma unroll
  for (int i = 0; i < 8; ++i) onesu.s[i] = 0x3F80;
  const bf16x8 onesv = onesu.v;

  const f32x16 z16 = {};
  f32x16 oacc[2][2] = {};   // [qh][dh]
  f32x16 lacc[2] = {};      // [qh]

  const int srow = tid >> 3;           // 0..31
  const int scol = (tid & 7) * 8;      // key offset for staging
  const int keyg = scol >> 4;          // 16-key group
  const int todd = (scol >> 3) & 1;
  const int vkb = keyg * 16 + todd * 4;  // pi-permuted base for V staging
  const u16* Kg = K + (size_t)bh * S_LEN * HDIM + (size_t)srow * HDIM + scol;
  const u16* Vg = Vt + (size_t)bh * HDIM * S_LEN + (size_t)srow * S_LEN + scol;
  const float* mrow = maskL + (size_t)b * S_LEN;

  for (int kt = 0; kt < S_LEN; kt += 64) {
    bf16x8 kv0 = *(const bf16x8*)(Kg + (size_t)kt * HDIM);
    bf16x8 kv1 = *(const bf16x8*)(Kg + (size_t)(kt + 32) * HDIM);
    union { bf16x8 v; uint32_t u[4]; } vv0, vv1;
    vv0.v = *(const bf16x8*)(Vg + kt);
    vv1.v = *(const bf16x8*)(Vg + (size_t)32 * S_LEN + kt);
    __syncthreads();
    *(bf16x8*)(Ks + srow * 72 + scol) = kv0;
    *(bf16x8*)(Ks + (srow + 32) * 72 + scol) = kv1;
    *(u32x2*)(Vs + srow * 72 + vkb) = (u32x2){vv0.u[0], vv0.u[1]};
    *(u32x2*)(Vs + srow * 72 + vkb + 8) = (u32x2){vv0.u[2], vv0.u[3]};
    *(u32x2*)(Vs + (srow + 32) * 72 + vkb) = (u32x2){vv1.u[0], vv1.u[1]};
    *(u32x2*)(Vs + (srow + 32) * 72 + vkb + 8) = (u32x2){vv1.u[2], vv1.u[3]};
    __syncthreads();

    uint32_t P[2][2][8];   // [T][qh][dword]
#pragma unroll
    for (int T = 0; T < 2; ++T) {
      bf16x8 kf[4];
#pragma unroll
      for (int c = 0; c < 4; ++c)
        kf[c] = *(const bf16x8*)(Ks + (T * 32 + l32) * 72 + c * 16 + hi * 8);
      f32x4 m4[4];
#pragma unroll
      for (int tq = 0; tq < 4; ++tq)
        m4[tq] = *(const f32x4*)(mrow + kt + T * 32 + tq * 8 + hi * 4);
#pragma unroll
      for (int qh = 0; qh < 2; ++qh) {
        f32x16 s = __builtin_amdgcn_mfma_f32_32x32x16_bf16(kf[0], aq[qh][0], z16, 0, 0, 0);
#pragma unroll
        for (int c = 1; c < 4; ++c)
          s = __builtin_amdgcn_mfma_f32_32x32x16_bf16(kf[c], aq[qh][c], s, 0, 0, 0);
#pragma unroll
        for (int tq = 0; tq < 4; ++tq) {
          float p0 = EXP2(fmaf(s[tq * 4 + 0], SC_L, m4[tq][0]));
          float p1 = EXP2(fmaf(s[tq * 4 + 1], SC_L, m4[tq][1]));
          float p2 = EXP2(fmaf(s[tq * 4 + 2], SC_L, m4[tq][2]));
          float p3 = EXP2(fmaf(s[tq * 4 + 3], SC_L, m4[tq][3]));
          P[T][qh][tq * 2] = packbf2(p0, p1);
          P[T][qh][tq * 2 + 1] = packbf2(p2, p3);
        }
      }
    }

#pragma unroll
    for (int c = 0; c < 4; ++c) {
      const int T = c >> 1, half = c & 1;
      bf16x8 vf[2];
#pragma unroll
      for (int dh = 0; dh < 2; ++dh)
        vf[dh] = *(const bf16x8*)(Vs + (dh * 32 + l32) * 72 + c * 16 + hi * 8);
#pragma unroll
      for (int qh = 0; qh < 2; ++qh) {
        union { uint32_t u[4]; bf16x8 v; } pf;
#pragma unroll
        for (int e = 0; e < 4; ++e) pf.u[e] = P[T][qh][half * 4 + e];
        oacc[qh][0] = __builtin_amdgcn_mfma_f32_32x32x16_bf16(pf.v, vf[0], oacc[qh][0], 0, 0, 0);
        oacc[qh][1] = __builtin_amdgcn_mfma_f32_32x32x16_bf16(pf.v, vf[1], oacc[qh][1], 0, 0, 0);
        lacc[qh] = __builtin_amdgcn_mfma_f32_32x32x16_bf16(pf.v, onesv, lacc[qh], 0, 0, 0);
      }
    }
  }

#pragma unroll
  for (int qh = 0; qh < 2; ++qh) {
#pragma unroll
    for (int reg = 0; reg < 16; ++reg) {
      const int q = qw0 + qh * 32 + (reg & 3) + 8 * (reg >> 2) + 4 * hi;
      const float inv = 1.0f / lacc[qh][reg];
      u16* cp = ctx + ((size_t)(b * S_LEN + q) * NHEAD + h) * HDIM;
      cp[l32] = f2bf(oacc[qh][0][reg] * inv);
      cp[32 + l32] = f2bf(oacc[qh][1][reg] * inv);
    }
  }
}

extern "C" void kernel_launch(void* const* d_in, const int* in_sizes, int n_in,
                              void* d_out, int out_size, void* d_ws, size_t ws_size,
                              hipStream_t stream) {
  const float* x = (const float*)d_in[0];
  const float* mask = (const float*)d_in[1];
  const float* Wq = (const float*)d_in[2];
  const float* bq = (const float*)d_in[3];
  const float* Wk = (const float*)d_in[4];
  const float* bk = (const float*)d_in[5];
  const float* Wv = (const float*)d_in[6];
  const float* bv = (const float*)d_in[7];
  const float* Wo = (const float*)d_in[8];
  const float* bo = (const float*)d_in[9];
  float* out = (float*)d_out;

  char* ws = (char*)d_ws;
  size_t off = 0;
  u16* xb = (u16*)(ws + off);    off += (size_t)MROWS * DMODEL * 2;
  u16* wall = (u16*)(ws + off);  off += (size_t)4 * DMODEL * DMODEL * 2;  // Wq,Wk,Wv,Wo transposed
  u16* Qh = (u16*)(ws + off);    off += (size_t)MROWS * DMODEL * 2;   // [B,NH,S,HD]
  u16* Kh = (u16*)(ws + off);    off += (size_t)MROWS * DMODEL * 2;
  u16* Vtb = (u16*)(ws + off);   off += (size_t)MROWS * DMODEL * 2;   // [B,NH,HD,S]
  u16* ctxb = (u16*)(ws + off);  off += (size_t)MROWS * DMODEL * 2;   // [B,S,D]
  float* mL = (float*)(ws + off); off += (size_t)BATCH * S_LEN * 4;
  (void)ws_size; (void)in_sizes; (void)n_in; (void)out_size;

  prep_kernel<<<dim3(NB_CVT + NB_W + BATCH * S_LEN / 256), dim3(256), 0, stream>>>(
      (const float4v*)x, (u32x2*)xb, Wq, Wk, Wv, Wo, wall, mask, mL);

  // fused QKV: 256^2 8-phase-style, N = 3072; V written transposed
  gemm256_qkv<<<dim3(MROWS / 256, 3 * DMODEL / 256), dim3(512), 0, stream>>>(
      xb, wall, bq, bk, bv, Qh, Kh, Vtb);

  attn4_kernel<<<dim3(S_LEN / 256, BATCH * NHEAD), dim3(256), 0, stream>>>(Qh, Kh, Vtb, mL, ctxb);

  gemm128<1><<<dim3(MROWS / 128, DMODEL / 128), dim3(256), 0, stream>>>(
      ctxb, wall + (size_t)3 * DMODEL * DMODEL, bo, bo, bo, (void*)out, (void*)out, (void*)out);
}

// Round 17
// 289.945 us; speedup vs baseline: 1.2144x; 1.2144x over previous
//
#include <hip/hip_runtime.h>
#include <cstdint>
#include <cstddef>

typedef unsigned short u16;
typedef __attribute__((ext_vector_type(8))) __bf16 bf16x8;
typedef __attribute__((ext_vector_type(4))) float f32x4;
typedef __attribute__((ext_vector_type(16))) float f32x16;
typedef __attribute__((ext_vector_type(2))) uint32_t u32x2;
typedef __attribute__((ext_vector_type(4))) float float4v;

#define BATCH 4
#define S_LEN 2048
#define DMODEL 1024
#define NHEAD 16
#define HDIM 64
#define MROWS (BATCH * S_LEN)   // 8192
#define LOG2E 1.4426950408889634f
#define SC_L (0.125f * LOG2E)   // 1/sqrt(64) * log2(e)

__device__ __forceinline__ u16 f2bf(float f) {
  uint32_t u = __float_as_uint(f);
  u += 0x7fffu + ((u >> 16) & 1u);   // RNE
  return (u16)(u >> 16);
}

#if __has_builtin(__builtin_amdgcn_cvt_pk_bf16_f32)
__device__ __forceinline__ uint32_t packbf2(float a, float b) {
  auto t = __builtin_amdgcn_cvt_pk_bf16_f32(a, b);
  uint32_t u;
  __builtin_memcpy(&u, &t, 4);
  return u;
}
#else
__device__ __forceinline__ uint32_t packbf2(float a, float b) {
  uint32_t ua = __float_as_uint(a) + 0x8000u;
  uint32_t ub = __float_as_uint(b) + 0x8000u;
  return (ub & 0xFFFF0000u) | (ua >> 16);
}
#endif

#if __has_builtin(__builtin_amdgcn_exp2f)
#define EXP2(x) __builtin_amdgcn_exp2f(x)
#else
#define EXP2(x) exp2f(x)
#endif

typedef __attribute__((address_space(1))) void gvoid_t;
typedef __attribute__((address_space(3))) void svoid_t;
__device__ __forceinline__ void gl_lds16(const void* g, void* s) {
  __builtin_amdgcn_global_load_lds((gvoid_t*)g, (svoid_t*)s, 16, 0, 0);
}

// ---------------- fused prep: x cvt (8192 blks) + W transpose/cvt (4096 blks)
//                  + mask*LOG2E (32 blks) ----------------
// R7 lesson: folding LOG2E into attn cost 5.6us (attn softmax path is
// latency-critical); the pre-scale lives here instead.
#define NB_CVT (MROWS * DMODEL / 4 / 256)   // 8192
#define NB_W   4096
__global__ __launch_bounds__(256) void prep_kernel(const float4v* __restrict__ x,
                                                   u32x2* __restrict__ xb,
                                                   const float* __restrict__ W0,
                                                   const float* __restrict__ W1,
                                                   const float* __restrict__ W2,
                                                   const float* __restrict__ W3,
                                                   u16* __restrict__ Wall,
                                                   const float* __restrict__ mask,
                                                   float* __restrict__ mL) {
  __shared__ float tile[32][33];
  const int bid = blockIdx.x;
  const int tid = threadIdx.x;
  if (bid < NB_CVT) {
    const int i = bid * 256 + tid;
    float4v v = x[i];
    u32x2 o;
    o.x = packbf2(v.x, v.y);
    o.y = packbf2(v.z, v.w);
    xb[i] = o;
    return;
  }
  if (bid >= NB_CVT + NB_W) {   // mask * log2e
    const int i = (bid - NB_CVT - NB_W) * 256 + tid;
    mL[i] = mask[i] * LOG2E;
    return;
  }
  const int r = bid - NB_CVT;        // 0..4095
  const int z = r >> 10;             // weight index
  const int rem = r & 1023;
  const float* W = (z == 0) ? W0 : (z == 1) ? W1 : (z == 2) ? W2 : W3;
  u16* Wt = Wall + (size_t)z * DMODEL * DMODEL;
  const int n0 = (rem & 31) * 32, k0 = (rem >> 5) * 32;
  const int xx = tid & 31, y = tid >> 5;   // flattened (32,8)
  for (int yy = y; yy < 32; yy += 8)
    tile[yy][xx] = W[(size_t)(k0 + yy) * DMODEL + n0 + xx];
  __syncthreads();
  for (int yy = y; yy < 32; yy += 8)
    Wt[(size_t)(n0 + yy) * DMODEL + k0 + xx] = f2bf(tile[xx][yy]);
}

// ---------------- m97-style GEMM, 2 K-subtiles per barrier round (R3, session best) ----------------
// MODE 0: fused QKV, N=3072. seg 0/1 -> Q/K head layout [B,NH,S,HD];
//         seg 2 -> V written TRANSPOSED [B,NH,HD,S] (feeds attention directly).
// MODE 1: N=1024, fp32 out row-major.
// Structure ledger - CLOSED, serial 128^2/BK64 wins ALL benched variants:
//   R3 serial 2-subtile (this): QKV ~85-88us. Best.
//   R5 2-phase + __syncthreads: +~20us (drains just-issued loads).
//   R6 T4 counted-vmcnt, runtime idx: +~10us (VALU addr overhead).
//   R8 T4 counted-vmcnt, unrolled static idx: +7.4us.
//   R14 256^2 + launch_bounds(512,2): 194us (reg-cap spill; NEVER pass a
//     2nd launch_bounds arg - R2/R13/R14 three strikes).
//   R16 256^2 8-phase (clean, no spill, setprio, literal idx): 152us -
//     16-way bank conflicts (28.3M, linear 128B-stride LDS rows) + 1 blk/CU
//     (128KB LDS) x 1.5 dispatch rounds + K=1024 = only 16 K-tiles to
//     amortize the deep pipeline. The 256^2 template's fixed costs exceed
//     its pipeline gain AT THESE SHAPES (it wins at 4096^3).
// NOTE: NO XCD swizzle (R1: chunked swizzle -> FETCH 137MB, +17us).
template <int MODE>
__global__ __launch_bounds__(256) void gemm128(const u16* __restrict__ A,
                                               const u16* __restrict__ Bt,
                                               const float* __restrict__ b0,
                                               const float* __restrict__ b1,
                                               const float* __restrict__ b2,
                                               void* __restrict__ o0,
                                               void* __restrict__ o1,
                                               void* __restrict__ o2) {
  __shared__ u16 As[2 * 128 * 32];   // [subtile][row][k32]
  __shared__ u16 Bs[2 * 128 * 32];
  const int tid = threadIdx.x;
  const int wid = tid >> 6;
  const int lane = tid & 63;
  const int l16 = lane & 15;
  const int g4 = lane >> 4;
  const int m0 = blockIdx.x * 128;
  const int n0 = blockIdx.y * 128;
  const int wm = (wid & 1) * 64;
  const int wn = (wid >> 1) * 64;

  const int srow = tid >> 2;
  const int sk = (tid & 3) * 8;
  const u16* gA = A + (size_t)(m0 + srow) * DMODEL + sk;
  const u16* gB = Bt + (size_t)(n0 + srow) * DMODEL + sk;
  char* sA = (char*)As + wid * 1024;
  char* sB = (char*)Bs + wid * 1024;

  f32x4 acc[4][4];
#pragma unroll
  for (int i = 0; i < 4; ++i)
#pragma unroll
    for (int j = 0; j < 4; ++j) acc[i][j] = (f32x4){0.f, 0.f, 0.f, 0.f};

  for (int k0 = 0; k0 < DMODEL; k0 += 64) {
    __syncthreads();
    // subtile 0: K = k0..k0+31
    gl_lds16(gA + k0, sA);
    gl_lds16(gA + (size_t)64 * DMODEL + k0, sA + 4096);
    gl_lds16(gB + k0, sB);
    gl_lds16(gB + (size_t)64 * DMODEL + k0, sB + 4096);
    // subtile 1: K = k0+32..k0+63 (second 8KB tile, identical layout)
    gl_lds16(gA + k0 + 32, sA + 8192);
    gl_lds16(gA + (size_t)64 * DMODEL + k0 + 32, sA + 12288);
    gl_lds16(gB + k0 + 32, sB + 8192);
    gl_lds16(gB + (size_t)64 * DMODEL + k0 + 32, sB + 12288);
    __syncthreads();

#pragma unroll
    for (int kk = 0; kk < 2; ++kk) {
      const u16* Ab = As + kk * 4096;
      const u16* Bb = Bs + kk * 4096;
      bf16x8 af[4], bfr[4];
#pragma unroll
      for (int i = 0; i < 4; ++i)
        af[i] = *(const bf16x8*)(Ab + (wm + i * 16 + l16) * 32 + g4 * 8);
#pragma unroll
      for (int j = 0; j < 4; ++j)
        bfr[j] = *(const bf16x8*)(Bb + (wn + j * 16 + l16) * 32 + g4 * 8);
#pragma unroll
      for (int i = 0; i < 4; ++i)
#pragma unroll
        for (int j = 0; j < 4; ++j)
          acc[i][j] = __builtin_amdgcn_mfma_f32_16x16x32_bf16(af[i], bfr[j],
                                                              acc[i][j], 0, 0, 0);
    }
  }

  const int seg = n0 >> 10;   // wave-uniform
  const float* bp = (MODE == 1 || seg == 0) ? b0 : (seg == 1 ? b1 : b2);
  void* op = (MODE == 1 || seg == 0) ? o0 : (seg == 1 ? o1 : o2);

#pragma unroll
  for (int i = 0; i < 4; ++i) {
#pragma unroll
    for (int j = 0; j < 4; ++j) {
      const int coll = n0 + wn + j * 16 + l16;
      const int cseg = coll & 1023;
      const float bval = bp[cseg];
#pragma unroll
      for (int r = 0; r < 4; ++r) {
        const int rowg = m0 + wm + i * 16 + g4 * 4 + r;
        const float v = acc[i][j][r] + bval;
        if (MODE == 0) {
          const int b = rowg >> 11, s = rowg & (S_LEN - 1);
          const int h = cseg >> 6, d = cseg & (HDIM - 1);
          if (seg == 2) {   // V transposed: [B,NH,HD,S]
            ((u16*)op)[(((size_t)(b * NHEAD + h) * HDIM + d) << 11) + s] = f2bf(v);
          } else {
            ((u16*)op)[((size_t)((b * NHEAD + h) * S_LEN + s) << 6) + d] = f2bf(v);
          }
        } else {
          ((float*)op)[(size_t)rowg * DMODEL + cseg] = v;
        }
      }
    }
  }
}

// ---------------- flash attention v4 (measured best: 94.2us, FINAL) ----------------
// 64 q per wave, 256 q per block. P stays in registers: the S^T C-layout,
// packed pairwise, is a valid A-fragment under key-permutation
// pi = [0,1,2,3,8,9,10,11 | 4,5,6,7,12,13,14,15]; V is staged into LDS with
// pi applied so PV B-fragments are contiguous b128 reads.
// CLOSED ledger (8 falsified variants): R1 dbuf/T14/T5 neutral; R2 reg-cap
// spill 3x; R4 32q/wave +13us; R7 in-loop LOG2E +5.6us; R9 lacc->VALU +6us
// (MFMA has slack, VALU/latency path binds); R10 KVBLK=128 +1.6us (drain
// scales with bytes, not rounds); R11 LDS-free direct-global 2.2x (LDS earns
// its barriers: converts coalesced->strided + shares tile across waves);
// R13 key-split 512-thread occupancy +13us (stall = intra-wave dependent
// chain, not occupancy). This schedule is the structural optimum here.
__global__ __launch_bounds__(256, 2) void attn4_kernel(const u16* __restrict__ Q,
                                                       const u16* __restrict__ K,
                                                       const u16* __restrict__ Vt,
                                                       const float* __restrict__ maskL,
                                                       u16* __restrict__ ctx) {
  __shared__ u16 Ks[64 * 72];   // [key][d]
  __shared__ u16 Vs[64 * 72];   // [d][key'] (pi-permuted keys)

  const int tid = threadIdx.x;
  const int wid = tid >> 6;
  const int lane = tid & 63;
  const int l32 = lane & 31;
  const int hi = lane >> 5;
  // XCD swizzle: 512 blocks, 8 q-blocks/head; 64 consecutive nf per XCD = 8 heads.
  const int flat = blockIdx.y * gridDim.x + blockIdx.x;
  const int nf = (flat & 7) * 64 + (flat >> 3);
  const int bx = nf & 7;
  const int bh = nf >> 3;
  const int b = bh >> 4;
  const int h = bh & 15;
  const int qw0 = bx * 256 + wid * 64;

  // Q B-fragments for both q-halves
  const u16* Qbase = Q + (size_t)bh * S_LEN * HDIM;
  bf16x8 aq[2][4];
#pragma unroll
  for (int qh = 0; qh < 2; ++qh)
#pragma unroll
    for (int c = 0; c < 4; ++c)
      aq[qh][c] = *(const bf16x8*)(Qbase + (size_t)(qw0 + qh * 32 + l32) * HDIM +
                                   c * 16 + hi * 8);

  union { u16 s[8]; bf16x8 v; } onesu;
#pragma unroll
  for (int i = 0; i < 8; ++i) onesu.s[i] = 0x3F80;
  const bf16x8 onesv = onesu.v;

  const f32x16 z16 = {};
  f32x16 oacc[2][2] = {};   // [qh][dh]
  f32x16 lacc[2] = {};      // [qh]

  const int srow = tid >> 3;           // 0..31
  const int scol = (tid & 7) * 8;      // key offset for staging
  const int keyg = scol >> 4;          // 16-key group
  const int todd = (scol >> 3) & 1;
  const int vkb = keyg * 16 + todd * 4;  // pi-permuted base for V staging
  const u16* Kg = K + (size_t)bh * S_LEN * HDIM + (size_t)srow * HDIM + scol;
  const u16* Vg = Vt + (size_t)bh * HDIM * S_LEN + (size_t)srow * S_LEN + scol;
  const float* mrow = maskL + (size_t)b * S_LEN;

  for (int kt = 0; kt < S_LEN; kt += 64) {
    bf16x8 kv0 = *(const bf16x8*)(Kg + (size_t)kt * HDIM);
    bf16x8 kv1 = *(const bf16x8*)(Kg + (size_t)(kt + 32) * HDIM);
    union { bf16x8 v; uint32_t u[4]; } vv0, vv1;
    vv0.v = *(const bf16x8*)(Vg + kt);
    vv1.v = *(const bf16x8*)(Vg + (size_t)32 * S_LEN + kt);
    __syncthreads();
    *(bf16x8*)(Ks + srow * 72 + scol) = kv0;
    *(bf16x8*)(Ks + (srow + 32) * 72 + scol) = kv1;
    // V with pi: keys {base..base+3} -> key' vkb, {base+4..7} -> key' vkb+8
    *(u32x2*)(Vs + srow * 72 + vkb) = (u32x2){vv0.u[0], vv0.u[1]};
    *(u32x2*)(Vs + srow * 72 + vkb + 8) = (u32x2){vv0.u[2], vv0.u[3]};
    *(u32x2*)(Vs + (srow + 32) * 72 + vkb) = (u32x2){vv1.u[0], vv1.u[1]};
    *(u32x2*)(Vs + (srow + 32) * 72 + vkb + 8) = (u32x2){vv1.u[2], vv1.u[3]};
    __syncthreads();

    uint32_t P[2][2][8];   // [T][qh][dword]
#pragma unroll
    for (int T = 0; T < 2; ++T) {
      bf16x8 kf[4];
#pragma unroll
      for (int c = 0; c < 4; ++c)
        kf[c] = *(const bf16x8*)(Ks + (T * 32 + l32) * 72 + c * 16 + hi * 8);
      f32x4 m4[4];
#pragma unroll
      for (int tq = 0; tq < 4; ++tq)
        m4[tq] = *(const f32x4*)(mrow + kt + T * 32 + tq * 8 + hi * 4);
#pragma unroll
      for (int qh = 0; qh < 2; ++qh) {
        f32x16 s = __builtin_amdgcn_mfma_f32_32x32x16_bf16(kf[0], aq[qh][0], z16, 0, 0, 0);
#pragma unroll
        for (int c = 1; c < 4; ++c)
          s = __builtin_amdgcn_mfma_f32_32x32x16_bf16(kf[c], aq[qh][c], s, 0, 0, 0);
#pragma unroll
        for (int tq = 0; tq < 4; ++tq) {
          float p0 = EXP2(fmaf(s[tq * 4 + 0], SC_L, m4[tq][0]));
          float p1 = EXP2(fmaf(s[tq * 4 + 1], SC_L, m4[tq][1]));
          float p2 = EXP2(fmaf(s[tq * 4 + 2], SC_L, m4[tq][2]));
          float p3 = EXP2(fmaf(s[tq * 4 + 3], SC_L, m4[tq][3]));
          P[T][qh][tq * 2] = packbf2(p0, p1);
          P[T][qh][tq * 2 + 1] = packbf2(p2, p3);
        }
      }
    }

    // PV + l: A = in-register P fragments, B = pi-permuted V from LDS
#pragma unroll
    for (int c = 0; c < 4; ++c) {
      const int T = c >> 1, half = c & 1;
      bf16x8 vf[2];
#pragma unroll
      for (int dh = 0; dh < 2; ++dh)
        vf[dh] = *(const bf16x8*)(Vs + (dh * 32 + l32) * 72 + c * 16 + hi * 8);
#pragma unroll
      for (int qh = 0; qh < 2; ++qh) {
        union { uint32_t u[4]; bf16x8 v; } pf;
#pragma unroll
        for (int e = 0; e < 4; ++e) pf.u[e] = P[T][qh][half * 4 + e];
        oacc[qh][0] = __builtin_amdgcn_mfma_f32_32x32x16_bf16(pf.v, vf[0], oacc[qh][0], 0, 0, 0);
        oacc[qh][1] = __builtin_amdgcn_mfma_f32_32x32x16_bf16(pf.v, vf[1], oacc[qh][1], 0, 0, 0);
        lacc[qh] = __builtin_amdgcn_mfma_f32_32x32x16_bf16(pf.v, onesv, lacc[qh], 0, 0, 0);
      }
    }
  }

  // epilogue: ctx [B,S,NH,HD]
#pragma unroll
  for (int qh = 0; qh < 2; ++qh) {
#pragma unroll
    for (int reg = 0; reg < 16; ++reg) {
      const int q = qw0 + qh * 32 + (reg & 3) + 8 * (reg >> 2) + 4 * hi;
      const float inv = 1.0f / lacc[qh][reg];
      u16* cp = ctx + ((size_t)(b * S_LEN + q) * NHEAD + h) * HDIM;
      cp[l32] = f2bf(oacc[qh][0][reg] * inv);
      cp[32 + l32] = f2bf(oacc[qh][1][reg] * inv);
    }
  }
}

extern "C" void kernel_launch(void* const* d_in, const int* in_sizes, int n_in,
                              void* d_out, int out_size, void* d_ws, size_t ws_size,
                              hipStream_t stream) {
  const float* x = (const float*)d_in[0];
  const float* mask = (const float*)d_in[1];
  const float* Wq = (const float*)d_in[2];
  const float* bq = (const float*)d_in[3];
  const float* Wk = (const float*)d_in[4];
  const float* bk = (const float*)d_in[5];
  const float* Wv = (const float*)d_in[6];
  const float* bv = (const float*)d_in[7];
  const float* Wo = (const float*)d_in[8];
  const float* bo = (const float*)d_in[9];
  float* out = (float*)d_out;

  char* ws = (char*)d_ws;
  size_t off = 0;
  u16* xb = (u16*)(ws + off);    off += (size_t)MROWS * DMODEL * 2;
  u16* wall = (u16*)(ws + off);  off += (size_t)4 * DMODEL * DMODEL * 2;  // Wq,Wk,Wv,Wo transposed
  u16* Qh = (u16*)(ws + off);    off += (size_t)MROWS * DMODEL * 2;   // [B,NH,S,HD]
  u16* Kh = (u16*)(ws + off);    off += (size_t)MROWS * DMODEL * 2;
  u16* Vtb = (u16*)(ws + off);   off += (size_t)MROWS * DMODEL * 2;   // [B,NH,HD,S]
  u16* ctxb = (u16*)(ws + off);  off += (size_t)MROWS * DMODEL * 2;   // [B,S,D]
  float* mL = (float*)(ws + off); off += (size_t)BATCH * S_LEN * 4;
  (void)ws_size; (void)in_sizes; (void)n_in; (void)out_size;

  prep_kernel<<<dim3(NB_CVT + NB_W + BATCH * S_LEN / 256), dim3(256), 0, stream>>>(
      (const float4v*)x, (u32x2*)xb, Wq, Wk, Wv, Wo, wall, mask, mL);

  // fused QKV: N = 3072; V written transposed
  gemm128<0><<<dim3(MROWS / 128, 3 * DMODEL / 128), dim3(256), 0, stream>>>(
      xb, wall, bq, bk, bv, (void*)Qh, (void*)Kh, (void*)Vtb);

  attn4_kernel<<<dim3(S_LEN / 256, BATCH * NHEAD), dim3(256), 0, stream>>>(Qh, Kh, Vtb, mL, ctxb);

  gemm128<1><<<dim3(MROWS / 128, DMODEL / 128), dim3(256), 0, stream>>>(
      ctxb, wall + (size_t)3 * DMODEL * DMODEL, bo, bo, bo, (void*)out, (void*)out, (void*)out);
}